// Round 12
// baseline (1169.316 us; speedup 1.0000x reference)
//
#include <hip/hip_runtime.h>

// kNN (K=5, 100 classes), two-stage:
//   convA/convB: f32 -> f16 pre-swizzled slab images (A: 256-row tiles,
//                B: 128-row tiles, BK=32). A stores NEGATED train; 17th slab:
//                A=+tsq/2 split (f16 hi/lo), B=[1,1,0...] => acc = d/2 >= 0.
//                Padded rows get +30000 => never selected.
//   knn_dma:     256x128 block tile, 4 waves (wave tile 128x64), 3 blocks/CU.
//                A: 3-buffer prefetch-distance-2 global_load_lds pipeline with
//                counted vmcnt. B: per-phase direct global->register loads
//                from the L2-resident pre-swizzled image (no LDS round-trip).
//                Branchless packed-key top-6 per (query,chunk) via v_med3_f32.
//   knn_final6:  exact fp32 rescore of 96 candidates -> top-5 lex -> mode.
// Fallback (small ws): R3 pipeline (in-loop convert), proven, own final kernel.

#define N_TEST   4096
#define N_TRAIN  100000
#define NT256    391         // ceil(100000/256)
#define NPAD     100096      // 391*256
#define DIM      512
#define KNN      5
#define NCH      16
#define TD6      6
#define TD8      8
#define PH       17          // 16 data slabs + 1 tsq-pad slab
#define ASLAB    16384       // 256 rows x 32 f16 cols
#define BSLAB    8192        // 128 rows x 32 f16 cols
#define INF      3.402823466e38f
#define IMAX     0x7fffffff

typedef __attribute__((ext_vector_type(8))) _Float16 f16x8;
typedef __attribute__((ext_vector_type(4))) _Float16 f16x4;
typedef __attribute__((ext_vector_type(4))) float    f32x4;

#if defined(__has_builtin) && __has_builtin(__builtin_amdgcn_fmed3f)
#define MED3(a,b,c) __builtin_amdgcn_fmed3f((a),(b),(c))
#else
#define MED3(a,b,c) fminf(fmaxf((a),fminf((b),(c))), fmaxf(fminf((a),(b)),(c)))
#endif

// ---- ws layout (DMA path) ----
#define WS_WSI   0u                       // 4096*96*4 = 1,572,864
#define WS_TSQ   2097152u
#define WS_AIMG  2500608u                 // 391*17*16384 = 108,904,448
#define WS_BIMG  111405056u               // 32*17*8192   =   4,456,448
#define WS_NEED  115861504u
// fallback layout: wsi@0 (TD8 fmt), tsq@2097152, wsd@2500608, xf@4597760

__device__ __forceinline__ void gload_lds16(const void* g, void* l) {
    __builtin_amdgcn_global_load_lds(
        (const __attribute__((address_space(1))) void*)g,
        (__attribute__((address_space(3))) void*)l, 16, 0, 0);
}

__device__ __forceinline__ bool bet(float d, int t, float dd, int tt) {
    return (d < dd) || (d == dd && t < tt);
}

__device__ __forceinline__ void ins6lex(float (&td)[TD6], int (&ti)[TD6], float d, int tg) {
    if (bet(d, tg, td[TD6 - 1], ti[TD6 - 1])) {
        td[TD6 - 1] = d; ti[TD6 - 1] = tg;
        #pragma unroll
        for (int j = TD6 - 1; j > 0; --j) {
            if (bet(td[j], ti[j], td[j - 1], ti[j - 1])) {
                float t0 = td[j]; td[j] = td[j - 1]; td[j - 1] = t0;
                int   i0 = ti[j]; ti[j] = ti[j - 1]; ti[j - 1] = i0;
            }
        }
    }
}

__device__ __forceinline__ void ins8(float (&td)[TD8], int (&ti)[TD8], float d, int tg) {
    if (d < td[TD8 - 1]) {
        td[TD8 - 1] = d; ti[TD8 - 1] = tg;
        #pragma unroll
        for (int j = TD8 - 1; j > 0; --j) {
            if (td[j] < td[j - 1]) {
                float t0 = td[j]; td[j] = td[j - 1]; td[j - 1] = t0;
                int   i0 = ti[j]; ti[j] = ti[j - 1]; ti[j - 1] = i0;
            }
        }
    }
}

__device__ __forceinline__ void ins8lex(float (&td)[TD8], int (&ti)[TD8], float d, int tg) {
    if (bet(d, tg, td[TD8 - 1], ti[TD8 - 1])) {
        td[TD8 - 1] = d; ti[TD8 - 1] = tg;
        #pragma unroll
        for (int j = TD8 - 1; j > 0; --j) {
            if (bet(td[j], ti[j], td[j - 1], ti[j - 1])) {
                float t0 = td[j]; td[j] = td[j - 1]; td[j - 1] = t0;
                int   i0 = ti[j]; ti[j] = ti[j - 1]; ti[j - 1] = i0;
            }
        }
    }
}

__device__ __forceinline__ void ins5lex(float (&td)[KNN], int (&ti)[KNN], float d, int tg) {
    if (bet(d, tg, td[4], ti[4])) {
        if (bet(d, tg, td[3], ti[3])) {
            td[4] = td[3]; ti[4] = ti[3];
            if (bet(d, tg, td[2], ti[2])) {
                td[3] = td[2]; ti[3] = ti[2];
                if (bet(d, tg, td[1], ti[1])) {
                    td[2] = td[1]; ti[2] = ti[1];
                    if (bet(d, tg, td[0], ti[0])) {
                        td[1] = td[0]; ti[1] = ti[0];
                        td[0] = d; ti[0] = tg;
                    } else { td[1] = d; ti[1] = tg; }
                } else { td[2] = d; ti[2] = tg; }
            } else { td[3] = d; ti[3] = tg; }
        } else { td[4] = d; ti[4] = tg; }
    }
}

// ================= conversion kernels (DMA path) =================
// one wave per padded row. Slab p (0..15): cols 32p..32p+31; slab 16: pad.
// byte offset within slab: r*64 + ((j ^ ((r>>1)&3))<<4), j = (col&31)>>3.
__global__ __launch_bounds__(256) void convA_kernel(const float* __restrict__ train,
        char* __restrict__ Aimg, float* __restrict__ tsq) {
    const int w    = threadIdx.x >> 6;
    const int lane = threadIdx.x & 63;
    const int rp   = blockIdx.x * 4 + w;
    const int rs   = min(rp, N_TRAIN - 1);
    const float4* src = (const float4*)(train + (size_t)rs * DIM + lane * 8);
    const float4 v0 = src[0], v1 = src[1];
    const float fv[8] = {v0.x, v0.y, v0.z, v0.w, v1.x, v1.y, v1.z, v1.w};
    float s = 0.0f;
    f16x8 h;
    #pragma unroll
    for (int e = 0; e < 8; ++e) { s += fv[e] * fv[e]; h[e] = (_Float16)(-fv[e]); }
    #pragma unroll
    for (int off = 32; off > 0; off >>= 1) s += __shfl_down(s, off, 64);
    s = __shfl(s, 0, 64);
    if (lane == 0 && rp < N_TRAIN) tsq[rp] = s;
    const int gt = rp >> 8, r = rp & 255;
    const int p = lane >> 2, j = lane & 3;
    const int xw = (r >> 1) & 3;
    char* base = Aimg + ((size_t)(gt * PH + p)) * ASLAB + r * 64;
    *(f16x8*)(base + ((j ^ xw) << 4)) = h;
    if (lane < 4) {
        f16x8 pad = {0, 0, 0, 0, 0, 0, 0, 0};
        if (lane == 0) {
            const float th = (rp < N_TRAIN) ? 0.5f * s : 30000.0f;
            const _Float16 h0 = (_Float16)th;
            pad[0] = h0;
            pad[1] = (_Float16)(th - (float)h0);
        }
        char* pb = Aimg + ((size_t)(gt * PH + 16)) * ASLAB + r * 64;
        *(f16x8*)(pb + ((lane ^ xw) << 4)) = pad;
    }
}

__global__ __launch_bounds__(256) void convB_kernel(const float* __restrict__ x,
        char* __restrict__ Bimg) {
    const int w    = threadIdx.x >> 6;
    const int lane = threadIdx.x & 63;
    const int rp   = blockIdx.x * 4 + w;          // 0..4095
    const float4* src = (const float4*)(x + (size_t)rp * DIM + lane * 8);
    const float4 v0 = src[0], v1 = src[1];
    const float fv[8] = {v0.x, v0.y, v0.z, v0.w, v1.x, v1.y, v1.z, v1.w};
    f16x8 h;
    #pragma unroll
    for (int e = 0; e < 8; ++e) h[e] = (_Float16)fv[e];
    const int gt = rp >> 7, r = rp & 127;          // 32 tiles of 128 rows
    const int p = lane >> 2, j = lane & 3;
    const int xw = (r >> 1) & 3;
    char* base = Bimg + ((size_t)(gt * PH + p)) * BSLAB + r * 64;
    *(f16x8*)(base + ((j ^ xw) << 4)) = h;
    if (lane < 4) {
        f16x8 pad = {0, 0, 0, 0, 0, 0, 0, 0};
        if (lane == 0) { pad[0] = (_Float16)1.0f; pad[1] = (_Float16)1.0f; }
        char* pb = Bimg + ((size_t)(gt * PH + 16)) * BSLAB + r * 64;
        *(f16x8*)(pb + ((lane ^ xw) << 4)) = pad;
    }
}

// ================= Stage A (DMA path) =================
// 256 threads / 4 waves, block tile 256 trains x 128 queries, wave 128x64.
// LDS: 3 A-buffers x 16KB = 48KB -> 3 blocks/CU (12 waves). B: per-phase
// global->register loads from the L2-resident image.
__global__ __launch_bounds__(256, 3)
void knn_dma(
    const char* __restrict__ Aimg, const char* __restrict__ Bimg,
    int* __restrict__ wsi)
{
    __shared__ __align__(16) char smem[49152];
    const int tid  = threadIdx.x;
    const int qt   = blockIdx.x;                // 0..31 (128-query tile)
    const int q0   = qt * 128;
    const int c    = blockIdx.y;                // 0..15
    const int gt0  = (c * NT256) >> 4;          // balanced partition (24/25 tiles)
    const int gt1  = ((c + 1) * NT256) >> 4;
    const int nt   = gt1 - gt0;
    const int tot  = nt * PH;

    const int w    = tid >> 6;                  // 0..3
    const int lane = tid & 63;
    const int wrow = w >> 1;                    // 0..1 : 128-row train half
    const int wcol = w & 1;                     // 0..1 : 64-col query half
    const int l15  = lane & 15;
    const int lk   = lane >> 4;                 // 0..3

    // fragment read offsets; xw depends only on l15 (invariant across mi/nj)
    const int xw    = (l15 >> 1) & 3;
    const int aoff  = (wrow * 128 + l15) * 64 + ((lk ^ xw) << 4);   // + mi*1024
    const int bgoff = (wcol * 64 + l15) * 64 + ((lk ^ xw) << 4);    // + nj*1024

    // branchless packed-key top-6 per query list (nj=0..3)
    float key[4][TD6];
    #pragma unroll
    for (int nj = 0; nj < 4; ++nj)
        #pragma unroll
        for (int j = 0; j < TD6; ++j) key[nj][j] = INF;

    // staging: A 16KB = 256 thr x 64B (4 DMA loads per stage)
    auto STAGE = [&](int buf, const char* a) {
        char* base = smem + buf * 16384;
        gload_lds16(a + tid * 16,         base + tid * 16);
        gload_lds16(a + tid * 16 + 4096,  base + tid * 16 + 4096);
        gload_lds16(a + tid * 16 + 8192,  base + tid * 16 + 8192);
        gload_lds16(a + tid * 16 + 12288, base + tid * 16 + 12288);
    };

    const char* aS = Aimg + (size_t)(gt0 * PH) * ASLAB;        // +ASLAB per stage
    const char* bP = Bimg + (size_t)(qt * PH) * BSLAB + bgoff; // + p*BSLAB + nj*1024

    STAGE(0, aS); aS += ASLAB;
    STAGE(1, aS); aS += ASLAB;
    int sp = 2;

    int gp = 0;
    #pragma unroll 1
    for (int at = 0; at < nt; ++at) {
        f32x4 acc[8][4];
        #pragma unroll
        for (int mi = 0; mi < 8; ++mi)
            #pragma unroll
            for (int nj = 0; nj < 4; ++nj) acc[mi][nj] = (f32x4){0.f, 0.f, 0.f, 0.f};

        #pragma unroll 1
        for (int p = 0; p < PH; ++p, ++gp) {
            // drain own A-DMA for the buffer about to be read (issued 2 phases
            // ago); keep the newest stage's 4 in flight.
            if (gp + 1 < tot) asm volatile("s_waitcnt vmcnt(4)" ::: "memory");
            else              asm volatile("s_waitcnt vmcnt(0)" ::: "memory");
            __builtin_amdgcn_s_barrier();       // publishes A buf[gp]
            __builtin_amdgcn_sched_barrier(0);

            // B operand: straight from L2-resident image to registers.
            // Issued BEFORE the A-DMA so the compiler's wait for vb is a
            // counted vmcnt that leaves the new stage in flight.
            f16x8 vb[4];
            {
                const char* bsl = bP + (size_t)p * BSLAB;
                #pragma unroll
                for (int nj = 0; nj < 4; ++nj)
                    vb[nj] = *(const f16x8*)(bsl + nj * 1024);
            }
            __builtin_amdgcn_sched_barrier(0);  // pin: B loads older than DMA

            // stage phase gp+2 into buf (gp+2)%3; its last readers finished
            // at phase gp-1 (before this barrier) => safe.
            if (sp < tot) { STAGE(sp % 3, aS); aS += ASLAB; ++sp; }

            const int bb = (gp % 3) * 16384;
            f16x8 va[8];
            #pragma unroll
            for (int mi = 0; mi < 8; ++mi)
                va[mi] = *(const f16x8*)(smem + bb + aoff + mi * 1024);

            __builtin_amdgcn_s_setprio(1);
            #pragma unroll
            for (int mi = 0; mi < 8; ++mi)
                #pragma unroll
                for (int nj = 0; nj < 4; ++nj)
                    acc[mi][nj] = __builtin_amdgcn_mfma_f32_16x16x32_f16(va[mi], vb[nj], acc[mi][nj], 0, 0, 0);
            __builtin_amdgcn_s_setprio(0);
        }

        // tile epilogue: d = acc (>=0; tsq folded, A negated).
        // key = (bits(d) & ~1023) | (at*32 + mi*4 + r)  [v_and_or_b32]
        // sorted top-6 insert via med3 chain (5 med3 + 1 min).
        const int atb = at << 5;
        #pragma unroll
        for (int mi = 0; mi < 8; ++mi) {
            #pragma unroll
            for (int r = 0; r < 4; ++r) {
                const unsigned idx = (unsigned)(atb + mi * 4 + r);
                #pragma unroll
                for (int nj = 0; nj < 4; ++nj) {
                    const float k = __uint_as_float(
                        (__float_as_uint(acc[mi][nj][r]) & 0xFFFFFC00u) | idx);
                    float* K = key[nj];
                    K[5] = MED3(K[4], K[5], k);
                    K[4] = MED3(K[3], K[4], k);
                    K[3] = MED3(K[2], K[3], k);
                    K[2] = MED3(K[1], K[2], k);
                    K[1] = MED3(K[0], K[1], k);
                    K[0] = fminf(K[0], k);
                }
            }
        }
    }

    // ---- block merge: 8 lists/query -> top-6/(query,chunk) -> wsi ----
    __syncthreads();                       // all GEMM LDS use done; reuse arena
    float* md = (float*)(smem);            // [48][128] f32 @0      (24KB)
    int*   mI = (int*)(smem + 24576);      // [48][128] i32 @24KB   (24KB)
    {
        const int slot = wrow * 4 + lk;    // 0..7
        #pragma unroll
        for (int nj = 0; nj < 4; ++nj) {
            const int qh = wcol * 64 + nj * 16 + l15;   // 0..127
            #pragma unroll
            for (int j = 0; j < TD6; ++j) {
                const unsigned kb = __float_as_uint(key[nj][j]);
                const int idx = (int)(kb & 1023u);
                const int tg  = (gt0 + (idx >> 5)) * 256 + wrow * 128
                              + ((idx >> 2) & 7) * 16 + lk * 4 + (idx & 3);
                md[(slot * TD6 + j) * 128 + qh] = key[nj][j];
                mI[(slot * TD6 + j) * 128 + qh] = tg;
            }
        }
    }
    __syncthreads();
    if (tid < 128) {
        float fd[TD6]; int fi[TD6];
        #pragma unroll
        for (int j = 0; j < TD6; ++j) { fd[j] = INF; fi[j] = IMAX; }
        #pragma unroll 1
        for (int s = 0; s < 48; ++s)
            ins6lex(fd, fi, md[s * 128 + tid], mI[s * 128 + tid]);
        const int q = q0 + tid;
        const size_t base = ((size_t)q * NCH + c) * TD6;
        #pragma unroll
        for (int j = 0; j < TD6; ++j) wsi[base + j] = fi[j];
    }
}

// ================= Stage B (DMA): exact rescore of 96 + mode =================
__global__ __launch_bounds__(256) void knn_final6(
    const float* __restrict__ x, const float* __restrict__ train,
    const float* __restrict__ tsq, const int* __restrict__ wsi,
    const int* __restrict__ labels, int* __restrict__ out)
{
    __shared__ float sc[96];
    __shared__ int   ci[96];
    const int q    = blockIdx.x;
    const int tid  = threadIdx.x;
    const int lane = tid & 63;
    const int w    = tid >> 6;

    const float4* xp = (const float4*)(x + (size_t)q * DIM);
    const float4 xa = xp[lane * 2], xb = xp[lane * 2 + 1];

    if (tid < 96) ci[tid] = wsi[(size_t)q * (NCH * TD6) + tid];
    __syncthreads();

    #pragma unroll 1
    for (int it = 0; it < 24; ++it) {
        const int cidx = w * 24 + it;
        const int t = min(ci[cidx], N_TRAIN - 1);
        const float4* tp = (const float4*)(train + (size_t)t * DIM);
        const float4 ta = tp[lane * 2], tb = tp[lane * 2 + 1];
        float s = ta.x*xa.x + ta.y*xa.y + ta.z*xa.z + ta.w*xa.w
                + tb.x*xb.x + tb.y*xb.y + tb.z*xb.z + tb.w*xb.w;
        #pragma unroll
        for (int off = 32; off > 0; off >>= 1) s += __shfl_down(s, off, 64);
        if (lane == 0) sc[cidx] = fmaf(-2.0f, s, tsq[t]);
    }
    __syncthreads();

    if (tid == 0) {
        float fd[KNN]; int fi[KNN];
        #pragma unroll
        for (int j = 0; j < KNN; ++j) { fd[j] = INF; fi[j] = IMAX; }
        #pragma unroll 1
        for (int s = 0; s < 96; ++s)
            if (ci[s] < N_TRAIN) ins5lex(fd, fi, sc[s], ci[s]);

        int lab[KNN];
        #pragma unroll
        for (int i = 0; i < KNN; ++i) lab[i] = labels[fi[i]];

        int bestLabel = IMAX, bestCount = 0;
        #pragma unroll
        for (int i = 0; i < KNN; ++i) {
            int cnt = 0;
            #pragma unroll
            for (int j = 0; j < KNN; ++j) cnt += (lab[j] == lab[i]) ? 1 : 0;
            if (cnt > bestCount || (cnt == bestCount && lab[i] < bestLabel)) {
                bestCount = cnt; bestLabel = lab[i];
            }
        }
        out[q] = bestLabel;
    }
}

// ================= fallback Stage A (R3, proven) =================
__global__ void tsq_kernel(const float* __restrict__ train, float* __restrict__ tsq) {
    const int lane = threadIdx.x & 63;
    const int wid  = (blockIdx.x * blockDim.x + threadIdx.x) >> 6;
    const int nw   = (gridDim.x * blockDim.x) >> 6;
    for (int row = wid; row < N_TRAIN; row += nw) {
        const float4* p = (const float4*)(train + (size_t)row * DIM);
        float4 a = p[lane];
        float4 b = p[lane + 64];
        float s = a.x*a.x + a.y*a.y + a.z*a.z + a.w*a.w
                + b.x*b.x + b.y*b.y + b.z*b.z + b.w*b.w;
        #pragma unroll
        for (int off = 32; off > 0; off >>= 1) s += __shfl_down(s, off, 64);
        if (lane == 0) tsq[row] = s;
    }
}

__global__ void xconv_kernel(const float* __restrict__ x, _Float16* __restrict__ xf) {
    const int i = blockIdx.x * blockDim.x + threadIdx.x;
    if (i >= N_TEST * DIM / 4) return;
    const float4 v = ((const float4*)x)[i];
    f16x4 h;
    h[0] = (_Float16)v.x; h[1] = (_Float16)v.y;
    h[2] = (_Float16)v.z; h[3] = (_Float16)v.w;
    ((f16x4*)xf)[i] = h;
}

__device__ __forceinline__ int fswz(int row, int kb) {
    return row * 128 + (kb ^ ((row & 7) << 4));
}

#define FB_TPC 6400
__global__ __launch_bounds__(256, 2) void knn_approx(
    const float* __restrict__ train, const _Float16* __restrict__ xf,
    const float* __restrict__ tsq,
    float* __restrict__ wsd, int* __restrict__ wsi)
{
    __shared__ __align__(16) char smem[33280];
    const int tid  = threadIdx.x;
    const int q0   = blockIdx.x * 128;
    const int c    = blockIdx.y;
    const int cstart = c * FB_TPC;
    const int nt   = min(FB_TPC >> 7, (N_TRAIN - cstart + 127) >> 7);
    const int w    = tid >> 6;
    const int wrow = w >> 1, wcol = w & 1;
    const int lane = tid & 63;
    const int l15  = lane & 15, lk = lane >> 4;
    const int srow = tid >> 1, sh = tid & 1;

    float td[4][TD8]; int ti[4][TD8];
    #pragma unroll
    for (int nj = 0; nj < 4; ++nj)
        #pragma unroll
        for (int j = 0; j < TD8; ++j) { td[nj][j] = INF; ti[nj][j] = IMAX; }

    for (int at = 0; at < nt; ++at) {
        const int tbase = cstart + at * 128;
        f32x4 acc[4][4];
        #pragma unroll
        for (int mi = 0; mi < 4; ++mi)
            #pragma unroll
            for (int nj = 0; nj < 4; ++nj) acc[mi][nj] = (f32x4){0.f, 0.f, 0.f, 0.f};

        const int trow_g = min(tbase + srow, N_TRAIN - 1);
        const float*    gA = train + (size_t)trow_g * DIM + sh * 32;
        const _Float16* gB = xf + (size_t)(q0 + srow) * DIM + sh * 32;
        float4 av[8]; f16x8 bv[4];
        #pragma unroll
        for (int j = 0; j < 8; ++j) av[j] = ((const float4*)gA)[j];
        #pragma unroll
        for (int j = 0; j < 4; ++j) bv[j] = ((const f16x8*)gB)[j];
        float tq = 0.0f;
        if (tid < 128) tq = tsq[min(tbase + tid, N_TRAIN - 1)];

        for (int kt = 0; kt < 8; ++kt) {
            __syncthreads();
            #pragma unroll
            for (int j = 0; j < 4; ++j) {
                const float4 v0 = av[2*j], v1 = av[2*j+1];
                const float fv[8] = {v0.x, v0.y, v0.z, v0.w, v1.x, v1.y, v1.z, v1.w};
                f16x8 h;
                #pragma unroll
                for (int e = 0; e < 8; ++e) h[e] = (_Float16)fv[e];
                const int kb = sh * 64 + j * 16;
                *(f16x8*)(smem + 0     + fswz(srow, kb)) = h;
                *(f16x8*)(smem + 16384 + fswz(srow, kb)) = bv[j];
            }
            if (kt == 0 && tid < 128) ((float*)(smem + 32768))[tid] = tq;
            __syncthreads();
            if (kt < 7) {
                const float*    pA = gA + (kt + 1) * 64;
                const _Float16* pB = gB + (kt + 1) * 64;
                #pragma unroll
                for (int j = 0; j < 8; ++j) av[j] = ((const float4*)pA)[j];
                #pragma unroll
                for (int j = 0; j < 4; ++j) bv[j] = ((const f16x8*)pB)[j];
            }
            #pragma unroll
            for (int kk = 0; kk < 2; ++kk) {
                const int kb = kk * 64 + lk * 16;
                f16x8 vb[4];
                #pragma unroll
                for (int nj = 0; nj < 4; ++nj)
                    vb[nj] = *(const f16x8*)(smem + 16384 + fswz(wcol * 64 + nj * 16 + l15, kb));
                #pragma unroll
                for (int mi = 0; mi < 4; ++mi) {
                    const f16x8 ah = *(const f16x8*)(smem + fswz(wrow * 64 + mi * 16 + l15, kb));
                    #pragma unroll
                    for (int nj = 0; nj < 4; ++nj)
                        acc[mi][nj] = __builtin_amdgcn_mfma_f32_16x16x32_f16(ah, vb[nj], acc[mi][nj], 0, 0, 0);
                }
            }
        }
        const float* tsqs = (const float*)(smem + 32768);
        #pragma unroll
        for (int nj = 0; nj < 4; ++nj)
            #pragma unroll
            for (int mi = 0; mi < 4; ++mi) {
                const int tloc = wrow * 64 + mi * 16 + lk * 4;
                #pragma unroll
                for (int r = 0; r < 4; ++r) {
                    const int tg = tbase + tloc + r;
                    if (tg < N_TRAIN) {
                        const float d = fmaf(-2.0f, acc[mi][nj][r], tsqs[tloc + r]);
                        ins8(td[nj], ti[nj], d, tg);
                    }
                }
            }
    }

    __syncthreads();
    float* md = (float*)(smem);
    int*   mI = (int*)(smem + 16384);
    for (int half = 0; half < 2; ++half) {
        if (half) __syncthreads();
        #pragma unroll
        for (int p = 0; p < 2; ++p) {
            const int nj   = half * 2 + p;
            const int qr   = wcol * 32 + p * 16 + l15;
            const int slot = wrow * 4 + lk;
            #pragma unroll
            for (int j = 0; j < TD8; ++j) {
                md[(slot * TD8 + j) * 64 + qr] = td[nj][j];
                mI[(slot * TD8 + j) * 64 + qr] = ti[nj][j];
            }
        }
        __syncthreads();
        if (tid < 64) {
            const int qr = tid;
            float fd[TD8]; int fi[TD8];
            #pragma unroll
            for (int j = 0; j < TD8; ++j) { fd[j] = INF; fi[j] = IMAX; }
            #pragma unroll 1
            for (int s = 0; s < 64; ++s)
                ins8lex(fd, fi, md[s * 64 + qr], mI[s * 64 + qr]);
            const int q = q0 + (qr >> 5) * 64 + (half * 2 + ((qr >> 4) & 1)) * 16 + (qr & 15);
            const size_t base = ((size_t)q * NCH + c) * TD8;
            #pragma unroll
            for (int j = 0; j < TD8; ++j) { wsd[base + j] = fd[j]; wsi[base + j] = fi[j]; }
        }
    }
}

// ================= fallback Stage B: rescore 128 + mode =================
__global__ __launch_bounds__(256) void knn_final_fb(
    const float* __restrict__ x, const float* __restrict__ train,
    const float* __restrict__ tsq, const int* __restrict__ wsi,
    const int* __restrict__ labels, int* __restrict__ out)
{
    __shared__ float sc[128];
    __shared__ int   ci[128];
    const int q    = blockIdx.x;
    const int tid  = threadIdx.x;
    const int lane = tid & 63;
    const int w    = tid >> 6;

    const float4* xp = (const float4*)(x + (size_t)q * DIM);
    const float4 xa = xp[lane * 2], xb = xp[lane * 2 + 1];

    if (tid < 128) ci[tid] = wsi[(size_t)q * (NCH * TD8) + tid];
    __syncthreads();

    #pragma unroll 1
    for (int it = 0; it < 32; ++it) {
        const int cidx = w * 32 + it;
        const int t = min(ci[cidx], N_TRAIN - 1);
        const float4* tp = (const float4*)(train + (size_t)t * DIM);
        const float4 ta = tp[lane * 2], tb = tp[lane * 2 + 1];
        float s = ta.x*xa.x + ta.y*xa.y + ta.z*xa.z + ta.w*xa.w
                + tb.x*xb.x + tb.y*xb.y + tb.z*xb.z + tb.w*xb.w;
        #pragma unroll
        for (int off = 32; off > 0; off >>= 1) s += __shfl_down(s, off, 64);
        if (lane == 0) sc[cidx] = fmaf(-2.0f, s, tsq[t]);
    }
    __syncthreads();

    if (tid == 0) {
        float fd[KNN]; int fi[KNN];
        #pragma unroll
        for (int j = 0; j < KNN; ++j) { fd[j] = INF; fi[j] = IMAX; }
        #pragma unroll 1
        for (int s = 0; s < 128; ++s)
            if (ci[s] < N_TRAIN) ins5lex(fd, fi, sc[s], ci[s]);

        int lab[KNN];
        #pragma unroll
        for (int i = 0; i < KNN; ++i) lab[i] = labels[fi[i]];

        int bestLabel = IMAX, bestCount = 0;
        #pragma unroll
        for (int i = 0; i < KNN; ++i) {
            int cnt = 0;
            #pragma unroll
            for (int j = 0; j < KNN; ++j) cnt += (lab[j] == lab[i]) ? 1 : 0;
            if (cnt > bestCount || (cnt == bestCount && lab[i] < bestLabel)) {
                bestCount = cnt; bestLabel = lab[i];
            }
        }
        out[q] = bestLabel;
    }
}

extern "C" void kernel_launch(void* const* d_in, const int* in_sizes, int n_in,
                              void* d_out, int out_size, void* d_ws, size_t ws_size,
                              hipStream_t stream) {
    const float* x      = (const float*)d_in[0];
    const float* train  = (const float*)d_in[1];
    const int*   labels = (const int*)d_in[2];
    int* out = (int*)d_out;
    char* ws = (char*)d_ws;

    int*   wsi = (int*)(ws + WS_WSI);
    float* tsq = (float*)(ws + WS_TSQ);

    if (ws_size >= (size_t)WS_NEED) {
        char* Aimg = ws + WS_AIMG;
        char* Bimg = ws + WS_BIMG;
        hipLaunchKernelGGL(convA_kernel, dim3(NPAD / 4), dim3(256), 0, stream, train, Aimg, tsq);
        hipLaunchKernelGGL(convB_kernel, dim3(N_TEST / 4), dim3(256), 0, stream, x, Bimg);
        hipLaunchKernelGGL(knn_dma, dim3(N_TEST / 128, NCH), dim3(256), 0, stream,
                           Aimg, Bimg, wsi);
        hipLaunchKernelGGL(knn_final6, dim3(N_TEST), dim3(256), 0, stream,
                           x, train, tsq, wsi, labels, out);
    } else {
        float*    wsd = (float*)(ws + 2500608);
        _Float16* xf  = (_Float16*)(ws + 4597760);
        hipLaunchKernelGGL(tsq_kernel, dim3(512), dim3(256), 0, stream, train, tsq);
        hipLaunchKernelGGL(xconv_kernel, dim3(N_TEST * DIM / 4 / 256), dim3(256), 0, stream, x, xf);
        hipLaunchKernelGGL(knn_approx, dim3(N_TEST / 128, NCH), dim3(256), 0, stream,
                           train, xf, tsq, wsd, wsi);
        hipLaunchKernelGGL(knn_final_fb, dim3(N_TEST), dim3(256), 0, stream,
                           x, train, tsq, wsi, labels, out);
    }
}

// Round 13
// 589.436 us; speedup vs baseline: 1.9838x; 1.9838x over previous
//
#include <hip/hip_runtime.h>

// kNN (K=5, 100 classes), two-stage:
//   convA/convB: f32 -> f16 pre-swizzled slab images (A: 256-row tiles,
//                B: 128-row tiles, BK=32). A stores NEGATED train; 17th slab:
//                A=+tsq/2 split (f16 hi/lo), B=[1,1,0...] => acc = d/2 >= 0.
//                Padded rows get +30000 => never selected.
//   knn_dma:     256x128 block tile, 4 waves (wave tile 128x64), 2 blocks/CU,
//                3-buffer prefetch-distance-2 global_load_lds pipeline,
//                counted vmcnt. Branchless packed-key top-6 per (query,chunk)
//                via v_med3_f32 sorted-insert chain.
//   knn_final6:  exact fp32 rescore of 96 candidates -> top-5 lex -> mode.
// Fallback (small ws): R3 pipeline (in-loop convert), proven, own final kernel.
//
// FINAL: R8/R11 configuration, verified three times at ~591 us total
// (knn_dma ~477 us, MfmaUtil 44%, VALUBusy 45%, no spill). Attempts to push
// further (8 waves, reg double-buffer, B-direct@3blk/CU) all regressed via
// measured mechanisms (issue latency / VGPR spill).

#define N_TEST   4096
#define N_TRAIN  100000
#define NT256    391         // ceil(100000/256)
#define NPAD     100096      // 391*256
#define DIM      512
#define KNN      5
#define NCH      16
#define TD6      6
#define TD8      8
#define PH       17          // 16 data slabs + 1 tsq-pad slab
#define ASLAB    16384       // 256 rows x 32 f16 cols
#define BSLAB    8192        // 128 rows x 32 f16 cols
#define INF      3.402823466e38f
#define IMAX     0x7fffffff

typedef __attribute__((ext_vector_type(8))) _Float16 f16x8;
typedef __attribute__((ext_vector_type(4))) _Float16 f16x4;
typedef __attribute__((ext_vector_type(4))) float    f32x4;

#if defined(__has_builtin) && __has_builtin(__builtin_amdgcn_fmed3f)
#define MED3(a,b,c) __builtin_amdgcn_fmed3f((a),(b),(c))
#else
#define MED3(a,b,c) fminf(fmaxf((a),fminf((b),(c))), fmaxf(fminf((a),(b)),(c)))
#endif

// ---- ws layout (DMA path) ----
#define WS_WSI   0u                       // 4096*96*4 = 1,572,864
#define WS_TSQ   2097152u
#define WS_AIMG  2500608u                 // 391*17*16384 = 108,904,448
#define WS_BIMG  111405056u               // 32*17*8192   =   4,456,448
#define WS_NEED  115861504u
// fallback layout: wsi@0 (TD8 fmt), tsq@2097152, wsd@2500608, xf@4597760

__device__ __forceinline__ void gload_lds16(const void* g, void* l) {
    __builtin_amdgcn_global_load_lds(
        (const __attribute__((address_space(1))) void*)g,
        (__attribute__((address_space(3))) void*)l, 16, 0, 0);
}

__device__ __forceinline__ bool bet(float d, int t, float dd, int tt) {
    return (d < dd) || (d == dd && t < tt);
}

__device__ __forceinline__ void ins6lex(float (&td)[TD6], int (&ti)[TD6], float d, int tg) {
    if (bet(d, tg, td[TD6 - 1], ti[TD6 - 1])) {
        td[TD6 - 1] = d; ti[TD6 - 1] = tg;
        #pragma unroll
        for (int j = TD6 - 1; j > 0; --j) {
            if (bet(td[j], ti[j], td[j - 1], ti[j - 1])) {
                float t0 = td[j]; td[j] = td[j - 1]; td[j - 1] = t0;
                int   i0 = ti[j]; ti[j] = ti[j - 1]; ti[j - 1] = i0;
            }
        }
    }
}

__device__ __forceinline__ void ins8(float (&td)[TD8], int (&ti)[TD8], float d, int tg) {
    if (d < td[TD8 - 1]) {
        td[TD8 - 1] = d; ti[TD8 - 1] = tg;
        #pragma unroll
        for (int j = TD8 - 1; j > 0; --j) {
            if (td[j] < td[j - 1]) {
                float t0 = td[j]; td[j] = td[j - 1]; td[j - 1] = t0;
                int   i0 = ti[j]; ti[j] = ti[j - 1]; ti[j - 1] = i0;
            }
        }
    }
}

__device__ __forceinline__ void ins8lex(float (&td)[TD8], int (&ti)[TD8], float d, int tg) {
    if (bet(d, tg, td[TD8 - 1], ti[TD8 - 1])) {
        td[TD8 - 1] = d; ti[TD8 - 1] = tg;
        #pragma unroll
        for (int j = TD8 - 1; j > 0; --j) {
            if (bet(td[j], ti[j], td[j - 1], ti[j - 1])) {
                float t0 = td[j]; td[j] = td[j - 1]; td[j - 1] = t0;
                int   i0 = ti[j]; ti[j] = ti[j - 1]; ti[j - 1] = i0;
            }
        }
    }
}

__device__ __forceinline__ void ins5lex(float (&td)[KNN], int (&ti)[KNN], float d, int tg) {
    if (bet(d, tg, td[4], ti[4])) {
        if (bet(d, tg, td[3], ti[3])) {
            td[4] = td[3]; ti[4] = ti[3];
            if (bet(d, tg, td[2], ti[2])) {
                td[3] = td[2]; ti[3] = ti[2];
                if (bet(d, tg, td[1], ti[1])) {
                    td[2] = td[1]; ti[2] = ti[1];
                    if (bet(d, tg, td[0], ti[0])) {
                        td[1] = td[0]; ti[1] = ti[0];
                        td[0] = d; ti[0] = tg;
                    } else { td[1] = d; ti[1] = tg; }
                } else { td[2] = d; ti[2] = tg; }
            } else { td[3] = d; ti[3] = tg; }
        } else { td[4] = d; ti[4] = tg; }
    }
}

// ================= conversion kernels (DMA path) =================
// one wave per padded row. Slab p (0..15): cols 32p..32p+31; slab 16: pad.
// byte offset within slab: r*64 + ((j ^ ((r>>1)&3))<<4), j = (col&31)>>3.
__global__ __launch_bounds__(256) void convA_kernel(const float* __restrict__ train,
        char* __restrict__ Aimg, float* __restrict__ tsq) {
    const int w    = threadIdx.x >> 6;
    const int lane = threadIdx.x & 63;
    const int rp   = blockIdx.x * 4 + w;
    const int rs   = min(rp, N_TRAIN - 1);
    const float4* src = (const float4*)(train + (size_t)rs * DIM + lane * 8);
    const float4 v0 = src[0], v1 = src[1];
    const float fv[8] = {v0.x, v0.y, v0.z, v0.w, v1.x, v1.y, v1.z, v1.w};
    float s = 0.0f;
    f16x8 h;
    #pragma unroll
    for (int e = 0; e < 8; ++e) { s += fv[e] * fv[e]; h[e] = (_Float16)(-fv[e]); }
    #pragma unroll
    for (int off = 32; off > 0; off >>= 1) s += __shfl_down(s, off, 64);
    s = __shfl(s, 0, 64);
    if (lane == 0 && rp < N_TRAIN) tsq[rp] = s;
    const int gt = rp >> 8, r = rp & 255;
    const int p = lane >> 2, j = lane & 3;
    const int xw = (r >> 1) & 3;
    char* base = Aimg + ((size_t)(gt * PH + p)) * ASLAB + r * 64;
    *(f16x8*)(base + ((j ^ xw) << 4)) = h;
    if (lane < 4) {
        f16x8 pad = {0, 0, 0, 0, 0, 0, 0, 0};
        if (lane == 0) {
            const float th = (rp < N_TRAIN) ? 0.5f * s : 30000.0f;
            const _Float16 h0 = (_Float16)th;
            pad[0] = h0;
            pad[1] = (_Float16)(th - (float)h0);
        }
        char* pb = Aimg + ((size_t)(gt * PH + 16)) * ASLAB + r * 64;
        *(f16x8*)(pb + ((lane ^ xw) << 4)) = pad;
    }
}

__global__ __launch_bounds__(256) void convB_kernel(const float* __restrict__ x,
        char* __restrict__ Bimg) {
    const int w    = threadIdx.x >> 6;
    const int lane = threadIdx.x & 63;
    const int rp   = blockIdx.x * 4 + w;          // 0..4095
    const float4* src = (const float4*)(x + (size_t)rp * DIM + lane * 8);
    const float4 v0 = src[0], v1 = src[1];
    const float fv[8] = {v0.x, v0.y, v0.z, v0.w, v1.x, v1.y, v1.z, v1.w};
    f16x8 h;
    #pragma unroll
    for (int e = 0; e < 8; ++e) h[e] = (_Float16)fv[e];
    const int gt = rp >> 7, r = rp & 127;          // 32 tiles of 128 rows
    const int p = lane >> 2, j = lane & 3;
    const int xw = (r >> 1) & 3;
    char* base = Bimg + ((size_t)(gt * PH + p)) * BSLAB + r * 64;
    *(f16x8*)(base + ((j ^ xw) << 4)) = h;
    if (lane < 4) {
        f16x8 pad = {0, 0, 0, 0, 0, 0, 0, 0};
        if (lane == 0) { pad[0] = (_Float16)1.0f; pad[1] = (_Float16)1.0f; }
        char* pb = Bimg + ((size_t)(gt * PH + 16)) * BSLAB + r * 64;
        *(f16x8*)(pb + ((lane ^ xw) << 4)) = pad;
    }
}

// ================= Stage A (DMA path) =================
// 256 threads / 4 waves, block tile 256 trains x 128 queries, wave 128x64.
// LDS: 3 buffers x (A 16KB + B 8KB) = 72KB  -> 2 blocks/CU.
__global__ __launch_bounds__(256, 2) __attribute__((amdgpu_waves_per_eu(2, 2)))
void knn_dma(
    const char* __restrict__ Aimg, const char* __restrict__ Bimg,
    int* __restrict__ wsi)
{
    __shared__ __align__(16) char smem[73728];
    const int tid  = threadIdx.x;
    const int qt   = blockIdx.x;                // 0..31 (128-query tile)
    const int q0   = qt * 128;
    const int c    = blockIdx.y;                // 0..15
    const int gt0  = (c * NT256) >> 4;          // balanced partition (24/25 tiles)
    const int gt1  = ((c + 1) * NT256) >> 4;
    const int nt   = gt1 - gt0;
    const int tot  = nt * PH;

    const int w    = tid >> 6;                  // 0..3
    const int lane = tid & 63;
    const int wrow = w >> 1;                    // 0..1 : 128-row train half
    const int wcol = w & 1;                     // 0..1 : 64-col query half
    const int l15  = lane & 15;
    const int lk   = lane >> 4;                 // 0..3

    // fragment read offsets; xw depends only on l15 (invariant across mi/nj)
    const int xw   = (l15 >> 1) & 3;
    const int aoff = (wrow * 128 + l15) * 64 + ((lk ^ xw) << 4);           // + mi*1024
    const int boff = (wcol * 64 + l15) * 64 + ((lk ^ xw) << 4) + ASLAB;    // + nj*1024

    // branchless packed-key top-6 per query list (nj=0..3)
    float key[4][TD6];
    #pragma unroll
    for (int nj = 0; nj < 4; ++nj)
        #pragma unroll
        for (int j = 0; j < TD6; ++j) key[nj][j] = INF;

    // staging: A 16KB = 256 thr x 64B (4 loads), B 8KB = 256 thr x 32B (2 loads)
    auto STAGE = [&](int buf, const char* a, const char* b) {
        char* base = smem + buf * 24576;
        gload_lds16(a + tid * 16,         base + tid * 16);
        gload_lds16(a + tid * 16 + 4096,  base + tid * 16 + 4096);
        gload_lds16(a + tid * 16 + 8192,  base + tid * 16 + 8192);
        gload_lds16(a + tid * 16 + 12288, base + tid * 16 + 12288);
        gload_lds16(b + tid * 16,         base + ASLAB + tid * 16);
        gload_lds16(b + tid * 16 + 4096,  base + ASLAB + tid * 16 + 4096);
    };

    const char* aS = Aimg + (size_t)(gt0 * PH) * ASLAB;   // +ASLAB per stage
    const char* bB = Bimg + (size_t)(qt * PH) * BSLAB;
    int sp = 0, sp17 = 0;

    STAGE(0, aS, bB);         aS += ASLAB; sp = 1; sp17 = 1;
    STAGE(1, aS, bB + BSLAB); aS += ASLAB; sp = 2; sp17 = 2;

    int gp = 0;
    #pragma unroll 1
    for (int at = 0; at < nt; ++at) {
        f32x4 acc[8][4];
        #pragma unroll
        for (int mi = 0; mi < 8; ++mi)
            #pragma unroll
            for (int nj = 0; nj < 4; ++nj) acc[mi][nj] = (f32x4){0.f, 0.f, 0.f, 0.f};

        #pragma unroll 1
        for (int p = 0; p < PH; ++p, ++gp) {
            // drain own loads for the buffer about to be read (issued 2 phases
            // ago); keep the newer 6 in flight.
            if (gp + 1 < tot) asm volatile("s_waitcnt vmcnt(6)" ::: "memory");
            else              asm volatile("s_waitcnt vmcnt(0)" ::: "memory");
            __builtin_amdgcn_s_barrier();       // all waves' loads for phase gp landed
            __builtin_amdgcn_sched_barrier(0);

            // stage phase gp+2 into buf (gp+2)%3; its last readers finished
            // at phase gp-1 (before this barrier) => safe.
            if (sp < tot) {
                STAGE(sp % 3, aS, bB + sp17 * BSLAB);
                aS += ASLAB; ++sp;
                ++sp17; if (sp17 == PH) sp17 = 0;
            }

            const int bb = (gp % 3) * 24576;
            f16x8 va[8], vb[4];
            #pragma unroll
            for (int nj = 0; nj < 4; ++nj)
                vb[nj] = *(const f16x8*)(smem + bb + boff + nj * 1024);
            #pragma unroll
            for (int mi = 0; mi < 8; ++mi)
                va[mi] = *(const f16x8*)(smem + bb + aoff + mi * 1024);

            __builtin_amdgcn_s_setprio(1);
            #pragma unroll
            for (int mi = 0; mi < 8; ++mi)
                #pragma unroll
                for (int nj = 0; nj < 4; ++nj)
                    acc[mi][nj] = __builtin_amdgcn_mfma_f32_16x16x32_f16(va[mi], vb[nj], acc[mi][nj], 0, 0, 0);
            __builtin_amdgcn_s_setprio(0);
        }

        // tile epilogue: d = acc (>=0; tsq folded, A negated).
        // key = (bits(d) & ~1023) | (at*32 + mi*4 + r)  [v_and_or_b32]
        // sorted top-6 insert via med3 chain (5 med3 + 1 min).
        const int atb = at << 5;
        #pragma unroll
        for (int mi = 0; mi < 8; ++mi) {
            #pragma unroll
            for (int r = 0; r < 4; ++r) {
                const unsigned idx = (unsigned)(atb + mi * 4 + r);
                #pragma unroll
                for (int nj = 0; nj < 4; ++nj) {
                    const float k = __uint_as_float(
                        (__float_as_uint(acc[mi][nj][r]) & 0xFFFFFC00u) | idx);
                    float* K = key[nj];
                    K[5] = MED3(K[4], K[5], k);
                    K[4] = MED3(K[3], K[4], k);
                    K[3] = MED3(K[2], K[3], k);
                    K[2] = MED3(K[1], K[2], k);
                    K[1] = MED3(K[0], K[1], k);
                    K[0] = fminf(K[0], k);
                }
            }
        }
    }

    // ---- block merge: 8 lists/query -> top-6/(query,chunk) -> wsi ----
    __syncthreads();                       // all GEMM LDS use done; reuse arena
    float* md = (float*)(smem);            // [48][128] f32 @0      (24KB)
    int*   mI = (int*)(smem + 24576);      // [48][128] i32 @24KB   (24KB)
    {
        const int slot = wrow * 4 + lk;    // 0..7
        #pragma unroll
        for (int nj = 0; nj < 4; ++nj) {
            const int qh = wcol * 64 + nj * 16 + l15;   // 0..127
            #pragma unroll
            for (int j = 0; j < TD6; ++j) {
                const unsigned kb = __float_as_uint(key[nj][j]);
                const int idx = (int)(kb & 1023u);
                const int tg  = (gt0 + (idx >> 5)) * 256 + wrow * 128
                              + ((idx >> 2) & 7) * 16 + lk * 4 + (idx & 3);
                md[(slot * TD6 + j) * 128 + qh] = key[nj][j];
                mI[(slot * TD6 + j) * 128 + qh] = tg;
            }
        }
    }
    __syncthreads();
    if (tid < 128) {
        float fd[TD6]; int fi[TD6];
        #pragma unroll
        for (int j = 0; j < TD6; ++j) { fd[j] = INF; fi[j] = IMAX; }
        #pragma unroll 1
        for (int s = 0; s < 48; ++s)
            ins6lex(fd, fi, md[s * 128 + tid], mI[s * 128 + tid]);
        const int q = q0 + tid;
        const size_t base = ((size_t)q * NCH + c) * TD6;
        #pragma unroll
        for (int j = 0; j < TD6; ++j) wsi[base + j] = fi[j];
    }
}

// ================= Stage B (DMA): exact rescore of 96 + mode =================
__global__ __launch_bounds__(256) void knn_final6(
    const float* __restrict__ x, const float* __restrict__ train,
    const float* __restrict__ tsq, const int* __restrict__ wsi,
    const int* __restrict__ labels, int* __restrict__ out)
{
    __shared__ float sc[96];
    __shared__ int   ci[96];
    const int q    = blockIdx.x;
    const int tid  = threadIdx.x;
    const int lane = tid & 63;
    const int w    = tid >> 6;

    const float4* xp = (const float4*)(x + (size_t)q * DIM);
    const float4 xa = xp[lane * 2], xb = xp[lane * 2 + 1];

    if (tid < 96) ci[tid] = wsi[(size_t)q * (NCH * TD6) + tid];
    __syncthreads();

    #pragma unroll 1
    for (int it = 0; it < 24; ++it) {
        const int cidx = w * 24 + it;
        const int t = min(ci[cidx], N_TRAIN - 1);
        const float4* tp = (const float4*)(train + (size_t)t * DIM);
        const float4 ta = tp[lane * 2], tb = tp[lane * 2 + 1];
        float s = ta.x*xa.x + ta.y*xa.y + ta.z*xa.z + ta.w*xa.w
                + tb.x*xb.x + tb.y*xb.y + tb.z*xb.z + tb.w*xb.w;
        #pragma unroll
        for (int off = 32; off > 0; off >>= 1) s += __shfl_down(s, off, 64);
        if (lane == 0) sc[cidx] = fmaf(-2.0f, s, tsq[t]);
    }
    __syncthreads();

    if (tid == 0) {
        float fd[KNN]; int fi[KNN];
        #pragma unroll
        for (int j = 0; j < KNN; ++j) { fd[j] = INF; fi[j] = IMAX; }
        #pragma unroll 1
        for (int s = 0; s < 96; ++s)
            if (ci[s] < N_TRAIN) ins5lex(fd, fi, sc[s], ci[s]);

        int lab[KNN];
        #pragma unroll
        for (int i = 0; i < KNN; ++i) lab[i] = labels[fi[i]];

        int bestLabel = IMAX, bestCount = 0;
        #pragma unroll
        for (int i = 0; i < KNN; ++i) {
            int cnt = 0;
            #pragma unroll
            for (int j = 0; j < KNN; ++j) cnt += (lab[j] == lab[i]) ? 1 : 0;
            if (cnt > bestCount || (cnt == bestCount && lab[i] < bestLabel)) {
                bestCount = cnt; bestLabel = lab[i];
            }
        }
        out[q] = bestLabel;
    }
}

// ================= fallback Stage A (R3, proven) =================
__global__ void tsq_kernel(const float* __restrict__ train, float* __restrict__ tsq) {
    const int lane = threadIdx.x & 63;
    const int wid  = (blockIdx.x * blockDim.x + threadIdx.x) >> 6;
    const int nw   = (gridDim.x * blockDim.x) >> 6;
    for (int row = wid; row < N_TRAIN; row += nw) {
        const float4* p = (const float4*)(train + (size_t)row * DIM);
        float4 a = p[lane];
        float4 b = p[lane + 64];
        float s = a.x*a.x + a.y*a.y + a.z*a.z + a.w*a.w
                + b.x*b.x + b.y*b.y + b.z*b.z + b.w*b.w;
        #pragma unroll
        for (int off = 32; off > 0; off >>= 1) s += __shfl_down(s, off, 64);
        if (lane == 0) tsq[row] = s;
    }
}

__global__ void xconv_kernel(const float* __restrict__ x, _Float16* __restrict__ xf) {
    const int i = blockIdx.x * blockDim.x + threadIdx.x;
    if (i >= N_TEST * DIM / 4) return;
    const float4 v = ((const float4*)x)[i];
    f16x4 h;
    h[0] = (_Float16)v.x; h[1] = (_Float16)v.y;
    h[2] = (_Float16)v.z; h[3] = (_Float16)v.w;
    ((f16x4*)xf)[i] = h;
}

__device__ __forceinline__ int fswz(int row, int kb) {
    return row * 128 + (kb ^ ((row & 7) << 4));
}

#define FB_TPC 6400
__global__ __launch_bounds__(256, 2) void knn_approx(
    const float* __restrict__ train, const _Float16* __restrict__ xf,
    const float* __restrict__ tsq,
    float* __restrict__ wsd, int* __restrict__ wsi)
{
    __shared__ __align__(16) char smem[33280];
    const int tid  = threadIdx.x;
    const int q0   = blockIdx.x * 128;
    const int c    = blockIdx.y;
    const int cstart = c * FB_TPC;
    const int nt   = min(FB_TPC >> 7, (N_TRAIN - cstart + 127) >> 7);
    const int w    = tid >> 6;
    const int wrow = w >> 1, wcol = w & 1;
    const int lane = tid & 63;
    const int l15  = lane & 15, lk = lane >> 4;
    const int srow = tid >> 1, sh = tid & 1;

    float td[4][TD8]; int ti[4][TD8];
    #pragma unroll
    for (int nj = 0; nj < 4; ++nj)
        #pragma unroll
        for (int j = 0; j < TD8; ++j) { td[nj][j] = INF; ti[nj][j] = IMAX; }

    for (int at = 0; at < nt; ++at) {
        const int tbase = cstart + at * 128;
        f32x4 acc[4][4];
        #pragma unroll
        for (int mi = 0; mi < 4; ++mi)
            #pragma unroll
            for (int nj = 0; nj < 4; ++nj) acc[mi][nj] = (f32x4){0.f, 0.f, 0.f, 0.f};

        const int trow_g = min(tbase + srow, N_TRAIN - 1);
        const float*    gA = train + (size_t)trow_g * DIM + sh * 32;
        const _Float16* gB = xf + (size_t)(q0 + srow) * DIM + sh * 32;
        float4 av[8]; f16x8 bv[4];
        #pragma unroll
        for (int j = 0; j < 8; ++j) av[j] = ((const float4*)gA)[j];
        #pragma unroll
        for (int j = 0; j < 4; ++j) bv[j] = ((const f16x8*)gB)[j];
        float tq = 0.0f;
        if (tid < 128) tq = tsq[min(tbase + tid, N_TRAIN - 1)];

        for (int kt = 0; kt < 8; ++kt) {
            __syncthreads();
            #pragma unroll
            for (int j = 0; j < 4; ++j) {
                const float4 v0 = av[2*j], v1 = av[2*j+1];
                const float fv[8] = {v0.x, v0.y, v0.z, v0.w, v1.x, v1.y, v1.z, v1.w};
                f16x8 h;
                #pragma unroll
                for (int e = 0; e < 8; ++e) h[e] = (_Float16)fv[e];
                const int kb = sh * 64 + j * 16;
                *(f16x8*)(smem + 0     + fswz(srow, kb)) = h;
                *(f16x8*)(smem + 16384 + fswz(srow, kb)) = bv[j];
            }
            if (kt == 0 && tid < 128) ((float*)(smem + 32768))[tid] = tq;
            __syncthreads();
            if (kt < 7) {
                const float*    pA = gA + (kt + 1) * 64;
                const _Float16* pB = gB + (kt + 1) * 64;
                #pragma unroll
                for (int j = 0; j < 8; ++j) av[j] = ((const float4*)pA)[j];
                #pragma unroll
                for (int j = 0; j < 4; ++j) bv[j] = ((const f16x8*)pB)[j];
            }
            #pragma unroll
            for (int kk = 0; kk < 2; ++kk) {
                const int kb = kk * 64 + lk * 16;
                f16x8 vb[4];
                #pragma unroll
                for (int nj = 0; nj < 4; ++nj)
                    vb[nj] = *(const f16x8*)(smem + 16384 + fswz(wcol * 64 + nj * 16 + l15, kb));
                #pragma unroll
                for (int mi = 0; mi < 4; ++mi) {
                    const f16x8 ah = *(const f16x8*)(smem + fswz(wrow * 64 + mi * 16 + l15, kb));
                    #pragma unroll
                    for (int nj = 0; nj < 4; ++nj)
                        acc[mi][nj] = __builtin_amdgcn_mfma_f32_16x16x32_f16(ah, vb[nj], acc[mi][nj], 0, 0, 0);
                }
            }
        }
        const float* tsqs = (const float*)(smem + 32768);
        #pragma unroll
        for (int nj = 0; nj < 4; ++nj)
            #pragma unroll
            for (int mi = 0; mi < 4; ++mi) {
                const int tloc = wrow * 64 + mi * 16 + lk * 4;
                #pragma unroll
                for (int r = 0; r < 4; ++r) {
                    const int tg = tbase + tloc + r;
                    if (tg < N_TRAIN) {
                        const float d = fmaf(-2.0f, acc[mi][nj][r], tsqs[tloc + r]);
                        ins8(td[nj], ti[nj], d, tg);
                    }
                }
            }
    }

    __syncthreads();
    float* md = (float*)(smem);
    int*   mI = (int*)(smem + 16384);
    for (int half = 0; half < 2; ++half) {
        if (half) __syncthreads();
        #pragma unroll
        for (int p = 0; p < 2; ++p) {
            const int nj   = half * 2 + p;
            const int qr   = wcol * 32 + p * 16 + l15;
            const int slot = wrow * 4 + lk;
            #pragma unroll
            for (int j = 0; j < TD8; ++j) {
                md[(slot * TD8 + j) * 64 + qr] = td[nj][j];
                mI[(slot * TD8 + j) * 64 + qr] = ti[nj][j];
            }
        }
        __syncthreads();
        if (tid < 64) {
            const int qr = tid;
            float fd[TD8]; int fi[TD8];
            #pragma unroll
            for (int j = 0; j < TD8; ++j) { fd[j] = INF; fi[j] = IMAX; }
            #pragma unroll 1
            for (int s = 0; s < 64; ++s)
                ins8lex(fd, fi, md[s * 64 + qr], mI[s * 64 + qr]);
            const int q = q0 + (qr >> 5) * 64 + (half * 2 + ((qr >> 4) & 1)) * 16 + (qr & 15);
            const size_t base = ((size_t)q * NCH + c) * TD8;
            #pragma unroll
            for (int j = 0; j < TD8; ++j) { wsd[base + j] = fd[j]; wsi[base + j] = fi[j]; }
        }
    }
}

// ================= fallback Stage B: rescore 128 + mode =================
__global__ __launch_bounds__(256) void knn_final_fb(
    const float* __restrict__ x, const float* __restrict__ train,
    const float* __restrict__ tsq, const int* __restrict__ wsi,
    const int* __restrict__ labels, int* __restrict__ out)
{
    __shared__ float sc[128];
    __shared__ int   ci[128];
    const int q    = blockIdx.x;
    const int tid  = threadIdx.x;
    const int lane = tid & 63;
    const int w    = tid >> 6;

    const float4* xp = (const float4*)(x + (size_t)q * DIM);
    const float4 xa = xp[lane * 2], xb = xp[lane * 2 + 1];

    if (tid < 128) ci[tid] = wsi[(size_t)q * (NCH * TD8) + tid];
    __syncthreads();

    #pragma unroll 1
    for (int it = 0; it < 32; ++it) {
        const int cidx = w * 32 + it;
        const int t = min(ci[cidx], N_TRAIN - 1);
        const float4* tp = (const float4*)(train + (size_t)t * DIM);
        const float4 ta = tp[lane * 2], tb = tp[lane * 2 + 1];
        float s = ta.x*xa.x + ta.y*xa.y + ta.z*xa.z + ta.w*xa.w
                + tb.x*xb.x + tb.y*xb.y + tb.z*xb.z + tb.w*xb.w;
        #pragma unroll
        for (int off = 32; off > 0; off >>= 1) s += __shfl_down(s, off, 64);
        if (lane == 0) sc[cidx] = fmaf(-2.0f, s, tsq[t]);
    }
    __syncthreads();

    if (tid == 0) {
        float fd[KNN]; int fi[KNN];
        #pragma unroll
        for (int j = 0; j < KNN; ++j) { fd[j] = INF; fi[j] = IMAX; }
        #pragma unroll 1
        for (int s = 0; s < 128; ++s)
            if (ci[s] < N_TRAIN) ins5lex(fd, fi, sc[s], ci[s]);

        int lab[KNN];
        #pragma unroll
        for (int i = 0; i < KNN; ++i) lab[i] = labels[fi[i]];

        int bestLabel = IMAX, bestCount = 0;
        #pragma unroll
        for (int i = 0; i < KNN; ++i) {
            int cnt = 0;
            #pragma unroll
            for (int j = 0; j < KNN; ++j) cnt += (lab[j] == lab[i]) ? 1 : 0;
            if (cnt > bestCount || (cnt == bestCount && lab[i] < bestLabel)) {
                bestCount = cnt; bestLabel = lab[i];
            }
        }
        out[q] = bestLabel;
    }
}

extern "C" void kernel_launch(void* const* d_in, const int* in_sizes, int n_in,
                              void* d_out, int out_size, void* d_ws, size_t ws_size,
                              hipStream_t stream) {
    const float* x      = (const float*)d_in[0];
    const float* train  = (const float*)d_in[1];
    const int*   labels = (const int*)d_in[2];
    int* out = (int*)d_out;
    char* ws = (char*)d_ws;

    int*   wsi = (int*)(ws + WS_WSI);
    float* tsq = (float*)(ws + WS_TSQ);

    if (ws_size >= (size_t)WS_NEED) {
        char* Aimg = ws + WS_AIMG;
        char* Bimg = ws + WS_BIMG;
        hipLaunchKernelGGL(convA_kernel, dim3(NPAD / 4), dim3(256), 0, stream, train, Aimg, tsq);
        hipLaunchKernelGGL(convB_kernel, dim3(N_TEST / 4), dim3(256), 0, stream, x, Bimg);
        hipLaunchKernelGGL(knn_dma, dim3(N_TEST / 128, NCH), dim3(256), 0, stream,
                           Aimg, Bimg, wsi);
        hipLaunchKernelGGL(knn_final6, dim3(N_TEST), dim3(256), 0, stream,
                           x, train, tsq, wsi, labels, out);
    } else {
        float*    wsd = (float*)(ws + 2500608);
        _Float16* xf  = (_Float16*)(ws + 4597760);
        hipLaunchKernelGGL(tsq_kernel, dim3(512), dim3(256), 0, stream, train, tsq);
        hipLaunchKernelGGL(xconv_kernel, dim3(N_TEST * DIM / 4 / 256), dim3(256), 0, stream, x, xf);
        hipLaunchKernelGGL(knn_approx, dim3(N_TEST / 128, NCH), dim3(256), 0, stream,
                           train, xf, tsq, wsd, wsi);
        hipLaunchKernelGGL(knn_final_fb, dim3(N_TEST), dim3(256), 0, stream,
                           x, train, tsq, wsi, labels, out);
    }
}